// Round 1
// baseline (967.414 us; speedup 1.0000x reference)
//
#include <hip/hip_runtime.h>
#include <hip/hip_bf16.h>
#include <cstdint>

#define M_DIM 8192
#define K_DIM 4096
#define N_DIM 11008
#define NGROUPS 32
#define BM 128
#define BN 128
#define BK 64
#define NTILE_N 86
#define NTILE_M 64
#define NBLOCKS (NTILE_N * NTILE_M)   /* 5504, divisible by 8 */

typedef __attribute__((ext_vector_type(4))) float f32x4;
typedef __attribute__((ext_vector_type(8))) __bf16 bf16x8;

__device__ __forceinline__ unsigned int f2bf(float f) {
  unsigned int u = __builtin_bit_cast(unsigned int, f);
  return (u + 0x7FFFu + ((u >> 16) & 1u)) >> 16;   // RNE f32->bf16
}
__device__ __forceinline__ unsigned int pk2(float lo, float hi) {
  return f2bf(lo) | (f2bf(hi) << 16);
}

// ---------------- prepass: A fp32 -> bf16 ----------------
__global__ __launch_bounds__(256) void cvtA_kernel(const float* __restrict__ in,
                                                   unsigned short* __restrict__ outA) {
  size_t g = (size_t)blockIdx.x * 256 + threadIdx.x;
  size_t base = g * 8;
  const float4* p = (const float4*)(in + base);
  float4 a = p[0], b = p[1];
  uint4 v;
  v.x = pk2(a.x, a.y); v.y = pk2(a.z, a.w);
  v.z = pk2(b.x, b.y); v.w = pk2(b.z, b.w);
  *(uint4*)(outA + base) = v;
}

// ---------------- prepass: W int codes * scale -> bf16 ----------------
__global__ __launch_bounds__(256) void dequantW_kernel(const int* __restrict__ w,
                                                       const float* __restrict__ sc,
                                                       unsigned short* __restrict__ outB) {
  size_t g = (size_t)blockIdx.x * 256 + threadIdx.x;
  size_t base = g * 8;                       // element index into [N][K]
  unsigned n = (unsigned)(base >> 12);       // /4096
  unsigned k = (unsigned)base & 4095u;
  float s = sc[n * NGROUPS + (k >> 7)];      // 8 consecutive k share a group
  const int4* p = (const int4*)(w + base);
  int4 c0 = p[0], c1 = p[1];
  uint4 v;
  v.x = pk2((float)c0.x * s, (float)c0.y * s);
  v.y = pk2((float)c0.z * s, (float)c0.w * s);
  v.z = pk2((float)c1.x * s, (float)c1.y * s);
  v.w = pk2((float)c1.z * s, (float)c1.w * s);
  *(uint4*)(outB + base) = v;
}

__device__ __forceinline__ void gload16(const void* g, void* l) {
  __builtin_amdgcn_global_load_lds((const __attribute__((address_space(1))) void*)g,
                                   (__attribute__((address_space(3))) void*)l,
                                   16, 0, 0);
}

// ---------------- GEMM: C = A * B^T + bias ----------------
// A: [M][K] bf16 (ws) or fp32 (inline), B rows are output cols: [N][K]
// 128x128 tile, BK=64, 4 waves (2x2), each wave 64x64 via 4x4 16x16x32 MFMA frags.
// LDS layout [row][64] bf16, XOR-swizzled at 16B-granule level: phys = log ^ (row&7).
template <bool FAST>
__global__ __launch_bounds__(256, 2) void gemm_kernel(
    const unsigned short* __restrict__ wsA, const unsigned short* __restrict__ wsB,
    const float* __restrict__ Ain, const int* __restrict__ Wcodes,
    const float* __restrict__ scales, const float* __restrict__ bias,
    float* __restrict__ out) {
  __shared__ unsigned short lsA[BM * BK];
  __shared__ unsigned short lsB[BN * BK];

  const int t = threadIdx.x;
  const int bid = blockIdx.x;
  // bijective XCD swizzle (NBLOCKS % 8 == 0)
  const int wg = (bid & 7) * (NBLOCKS / 8) + (bid >> 3);
  const int mtile = wg / NTILE_N;
  const int ntile = wg % NTILE_N;
  const int m0 = mtile * BM;
  const int n0 = ntile * BN;

  const int w = t >> 6;
  const int lane = t & 63;
  const int wm = w >> 1, wn = w & 1;

  // staging coords: thread t covers physical granule (row = c*32 + t/8, p = t&7)
  const int srow = t >> 3;              // 0..31
  const int sp = t & 7;                 // physical 16B granule
  const int skc = sp ^ (srow & 7);      // logical granule fetched into that slot

  f32x4 acc[4][4];
#pragma unroll
  for (int i = 0; i < 4; ++i)
#pragma unroll
    for (int j = 0; j < 4; ++j) {
      f32x4 z = {0.f, 0.f, 0.f, 0.f};
      acc[i][j] = z;
    }

  const unsigned short* aS = FAST ? (wsA + (size_t)(m0 + srow) * K_DIM + skc * 8) : nullptr;
  const unsigned short* bS = FAST ? (wsB + (size_t)(n0 + srow) * K_DIM + skc * 8) : nullptr;
  unsigned short* la = lsA + (w * 8) * BK;   // wave-uniform LDS dest base
  unsigned short* lb = lsB + (w * 8) * BK;

  for (int kt = 0; kt < K_DIM / BK; ++kt) {
    if constexpr (FAST) {
#pragma unroll
      for (int c = 0; c < 4; ++c) {
        gload16(aS + (size_t)c * 32 * K_DIM, la + c * 32 * BK);
        gload16(bS + (size_t)c * 32 * K_DIM, lb + c * 32 * BK);
      }
      aS += BK;
      bS += BK;
    } else {
      const int kg = kt * BK + skc * 8;
#pragma unroll
      for (int c = 0; c < 4; ++c) {
        const int arow = m0 + c * 32 + srow;
        const float* ap = Ain + (size_t)arow * K_DIM + kg;
        float4 a0 = *(const float4*)ap;
        float4 a1 = *(const float4*)(ap + 4);
        uint4 va;
        va.x = pk2(a0.x, a0.y); va.y = pk2(a0.z, a0.w);
        va.z = pk2(a1.x, a1.y); va.w = pk2(a1.z, a1.w);
        *(uint4*)&lsA[(c * 32 + srow) * BK + sp * 8] = va;

        const int nrow = n0 + c * 32 + srow;
        const float s = scales[nrow * NGROUPS + (kg >> 7)];
        const int4* wp = (const int4*)(Wcodes + (size_t)nrow * K_DIM + kg);
        int4 c0 = wp[0], c1 = wp[1];
        uint4 vb;
        vb.x = pk2((float)c0.x * s, (float)c0.y * s);
        vb.y = pk2((float)c0.z * s, (float)c0.w * s);
        vb.z = pk2((float)c1.x * s, (float)c1.y * s);
        vb.w = pk2((float)c1.z * s, (float)c1.w * s);
        *(uint4*)&lsB[(c * 32 + srow) * BK + sp * 8] = vb;
      }
    }
    __syncthreads();

#pragma unroll
    for (int kk = 0; kk < 2; ++kk) {
      bf16x8 af[4], bfr[4];
#pragma unroll
      for (int i = 0; i < 4; ++i) {
        const int row = wm * 64 + i * 16 + (lane & 15);
        const int pg = (kk * 4 + (lane >> 4)) ^ (row & 7);
        af[i] = *(const bf16x8*)&lsA[row * BK + pg * 8];
      }
#pragma unroll
      for (int j = 0; j < 4; ++j) {
        const int row = wn * 64 + j * 16 + (lane & 15);
        const int pg = (kk * 4 + (lane >> 4)) ^ (row & 7);
        bfr[j] = *(const bf16x8*)&lsB[row * BK + pg * 8];
      }
#pragma unroll
      for (int i = 0; i < 4; ++i)
#pragma unroll
        for (int j = 0; j < 4; ++j)
          acc[i][j] = __builtin_amdgcn_mfma_f32_16x16x32_bf16(af[i], bfr[j], acc[i][j], 0, 0, 0);
    }
    __syncthreads();
  }

  // epilogue: D col = lane&15, row = (lane>>4)*4 + r
  const int colb = n0 + wn * 64 + (lane & 15);
  const int rowb = m0 + wm * 64 + ((lane >> 4) << 2);
#pragma unroll
  for (int j = 0; j < 4; ++j) {
    const int col = colb + j * 16;
    const float bv = bias[col];
#pragma unroll
    for (int i = 0; i < 4; ++i) {
      const int row = rowb + i * 16;
#pragma unroll
      for (int r = 0; r < 4; ++r)
        out[(size_t)(row + r) * N_DIM + col] = acc[i][j][r] + bv;
    }
  }
}

extern "C" void kernel_launch(void* const* d_in, const int* in_sizes, int n_in,
                              void* d_out, int out_size, void* d_ws, size_t ws_size,
                              hipStream_t stream) {
  const float* Ain = (const float*)d_in[0];
  const int* Wc = (const int*)d_in[1];
  const float* sc = (const float*)d_in[2];
  const float* bias = (const float*)d_in[3];
  float* out = (float*)d_out;

  const size_t needA = (size_t)M_DIM * K_DIM * 2;   // 64 MiB bf16 A
  const size_t needB = (size_t)N_DIM * K_DIM * 2;   // 86 MiB bf16 W
  if (ws_size >= needA + needB) {
    unsigned short* wsA = (unsigned short*)d_ws;
    unsigned short* wsB = (unsigned short*)((char*)d_ws + needA);
    cvtA_kernel<<<(unsigned)((size_t)M_DIM * K_DIM / 8 / 256), 256, 0, stream>>>(Ain, wsA);
    dequantW_kernel<<<(unsigned)((size_t)N_DIM * K_DIM / 8 / 256), 256, 0, stream>>>(Wc, sc, wsB);
    gemm_kernel<true><<<NBLOCKS, 256, 0, stream>>>(wsA, wsB, nullptr, nullptr, nullptr, bias, out);
  } else {
    gemm_kernel<false><<<NBLOCKS, 256, 0, stream>>>(nullptr, nullptr, Ain, Wc, sc, bias, out);
  }
}

// Round 2
// 886.079 us; speedup vs baseline: 1.0918x; 1.0918x over previous
//
#include <hip/hip_runtime.h>
#include <hip/hip_bf16.h>
#include <cstdint>

#define M_DIM 8192
#define K_DIM 4096
#define N_DIM 11008
#define NGROUPS 32

typedef __attribute__((ext_vector_type(4))) float f32x4;
typedef __attribute__((ext_vector_type(8))) __bf16 bf16x8;

__device__ __forceinline__ unsigned int f2bf(float f) {
  unsigned int u = __builtin_bit_cast(unsigned int, f);
  return (u + 0x7FFFu + ((u >> 16) & 1u)) >> 16;   // RNE f32->bf16
}
__device__ __forceinline__ unsigned int pk2(float lo, float hi) {
  return f2bf(lo) | (f2bf(hi) << 16);
}

// ---------------- prepass: A fp32 -> bf16 ----------------
__global__ __launch_bounds__(256) void cvtA_kernel(const float* __restrict__ in,
                                                   unsigned short* __restrict__ outA) {
  size_t g = (size_t)blockIdx.x * 256 + threadIdx.x;
  size_t base = g * 8;
  const float4* p = (const float4*)(in + base);
  float4 a = p[0], b = p[1];
  uint4 v;
  v.x = pk2(a.x, a.y); v.y = pk2(a.z, a.w);
  v.z = pk2(b.x, b.y); v.w = pk2(b.z, b.w);
  *(uint4*)(outA + base) = v;
}

// ---------------- prepass: W int codes * scale -> bf16 ----------------
__global__ __launch_bounds__(256) void dequantW_kernel(const int* __restrict__ w,
                                                       const float* __restrict__ sc,
                                                       unsigned short* __restrict__ outB) {
  size_t g = (size_t)blockIdx.x * 256 + threadIdx.x;
  size_t base = g * 8;                       // element index into [N][K]
  unsigned n = (unsigned)(base >> 12);       // /4096
  unsigned k = (unsigned)base & 4095u;
  float s = sc[n * NGROUPS + (k >> 7)];
  const int4* p = (const int4*)(w + base);
  int4 c0 = p[0], c1 = p[1];
  uint4 v;
  v.x = pk2((float)c0.x * s, (float)c0.y * s);
  v.y = pk2((float)c0.z * s, (float)c0.w * s);
  v.z = pk2((float)c1.x * s, (float)c1.y * s);
  v.w = pk2((float)c1.z * s, (float)c1.w * s);
  *(uint4*)(outB + base) = v;
}

__device__ __forceinline__ void gload16(const void* g, void* l) {
  __builtin_amdgcn_global_load_lds((const __attribute__((address_space(1))) void*)g,
                                   (__attribute__((address_space(3))) void*)l,
                                   16, 0, 0);
}

// ================= 256x256 8-phase GEMM (T1+T2+T3+T4+T5) =================
#define BM 256
#define BN 256
#define BK 64
#define NKT (K_DIM / BK)          /* 64 */
#define TILES_M (M_DIM / BM)      /* 32 */
#define TILES_N (N_DIM / BN)      /* 43 */
#define NB2 (TILES_M * TILES_N)   /* 1376, %8==0 */

#define VMCNT_(n) asm volatile("s_waitcnt vmcnt(" #n ")" ::: "memory")
#define VMCNT(n) VMCNT_(n)
#define BAR() __builtin_amdgcn_s_barrier()

__global__ __launch_bounds__(512, 2) void gemm8_kernel(
    const unsigned short* __restrict__ A,   // bf16 [M][K]
    const unsigned short* __restrict__ B,   // bf16 [N][K]
    const float* __restrict__ bias,
    float* __restrict__ out) {
  __shared__ unsigned short sA[2][BM * BK];
  __shared__ unsigned short sB[2][BN * BK];

  const int t = threadIdx.x;
  const int bid = blockIdx.x;
  const int wg = (bid & 7) * (NB2 / 8) + (bid >> 3);   // bijective XCD swizzle
  const int m0 = (wg / TILES_N) * BM;
  const int n0 = (wg % TILES_N) * BN;

  const int w = t >> 6;
  const int lane = t & 63;
  const int wm = w >> 2;   // 0..1
  const int wn = w & 3;    // 0..3

  // ---- staging geometry: per K-tile each thread issues A loads 0..3, B loads 0..3
  // order [A0,B0 | A1,B1 | B2,B3 | A2,A3] so that:
  //   A0,A1 cover rows [0,64)u[128,192)  (quadrant-0 of both halves, needed ph0)
  //   A2,A3 cover rows [64,128)u[192,256) (quadrant-1, needed ph2)
  //   B0,B1 cover rows {64h+[0,32)}      (phase-0 col-sets, needed ph0)
  //   B2,B3 cover rows {64h+32+[0,32)}   (phase-1 col-sets, needed ph1)
  const int lr = lane >> 3;            // row within 8-row block
  const int gsw = (lane & 7) ^ lr;     // pre-swizzled logical granule (rule #21)
  int rowA[4], rowB[4];
  unsigned offA[4], offB[4];
#pragma unroll
  for (int l = 0; l < 4; ++l) {
    const int idx = (w << 1) | (l & 1);        // 0..15
    const int bq = (l >> 1) * 64;
    rowA[l] = (idx < 8) ? (bq + idx * 8) : (128 + bq + (idx - 8) * 8);
    rowB[l] = (idx >> 2) * 64 + (l >> 1) * 32 + (idx & 3) * 8;
    offA[l] = (unsigned)(m0 + rowA[l] + lr) * K_DIM + gsw * 8;
    offB[l] = (unsigned)(n0 + rowB[l] + lr) * K_DIM + gsw * 8;
  }

  f32x4 acc[8][4];
#pragma unroll
  for (int i = 0; i < 8; ++i)
#pragma unroll
    for (int j = 0; j < 4; ++j) {
      f32x4 z = {0.f, 0.f, 0.f, 0.f};
      acc[i][j] = z;
    }
  bf16x8 Ar[4][2], Br[4][2];

  const int arow_base = wm * 128 + (lane & 15);
  const int brow_base = wn * 64 + (lane & 15);
  const int kgr = lane >> 4;

#define STAGE_A(buf, kt1, l) gload16(A + offA[l] + (unsigned)(kt1) * BK, &sA[buf][rowA[l] * BK])
#define STAGE_B(buf, kt1, l) gload16(B + offB[l] + (unsigned)(kt1) * BK, &sB[buf][rowB[l] * BK])

#define READ_A(buf, qi)                                                        \
  _Pragma("unroll") for (int i = 0; i < 4; ++i) {                              \
    const int row = arow_base + (qi) * 64 + i * 16;                            \
    _Pragma("unroll") for (int kk = 0; kk < 2; ++kk) {                         \
      const int pg = (kk * 4 + kgr) ^ (row & 7);                               \
      Ar[i][kk] = *(const bf16x8*)&sA[buf][row * BK + pg * 8];                 \
    }                                                                          \
  }

#define READ_B(buf, qj)                                                        \
  _Pragma("unroll") for (int jj = 0; jj < 2; ++jj) {                           \
    const int row = brow_base + ((qj) * 2 + jj) * 16;                          \
    _Pragma("unroll") for (int kk = 0; kk < 2; ++kk) {                         \
      const int pg = (kk * 4 + kgr) ^ (row & 7);                               \
      Br[(qj) * 2 + jj][kk] = *(const bf16x8*)&sB[buf][row * BK + pg * 8];     \
    }                                                                          \
  }

#define MMA(qi, qj)                                                            \
  __builtin_amdgcn_s_setprio(1);                                               \
  _Pragma("unroll") for (int i = 0; i < 4; ++i)                                \
  _Pragma("unroll") for (int jj = 0; jj < 2; ++jj)                             \
  _Pragma("unroll") for (int kk = 0; kk < 2; ++kk)                             \
    acc[(qi) * 4 + i][(qj) * 2 + jj] = __builtin_amdgcn_mfma_f32_16x16x32_bf16(\
        Ar[i][kk], Br[(qj) * 2 + jj][kk], acc[(qi) * 4 + i][(qj) * 2 + jj],    \
        0, 0, 0);                                                              \
  __builtin_amdgcn_s_setprio(0);

  // prologue: stage K-tile 0, full drain once
#pragma unroll
  for (int l = 0; l < 4; ++l) { STAGE_A(0, 0, l); STAGE_B(0, 0, l); }
  VMCNT(0);
  BAR();

  for (int kt = 0; kt < NKT - 1; ++kt) {
    const int cur = kt & 1, nxt = cur ^ 1;
    const int k1 = kt + 1;
    // ph0: quadrant (0,0)
    READ_A(cur, 0); READ_B(cur, 0);
    STAGE_A(nxt, k1, 0); STAGE_B(nxt, k1, 0);
    BAR();
    MMA(0, 0);
    VMCNT(4); BAR();          // guards B2,B3 of this K-tile for ph1
    // ph1: quadrant (0,1)
    READ_B(cur, 1);
    STAGE_A(nxt, k1, 1); STAGE_B(nxt, k1, 1);
    BAR();
    MMA(0, 1);
    VMCNT(4); BAR();          // guards A2,A3 of this K-tile for ph2
    // ph2: quadrant (1,0)
    READ_A(cur, 1);
    STAGE_B(nxt, k1, 2); STAGE_B(nxt, k1, 3);
    BAR();
    MMA(1, 0);
    BAR();
    // ph3: quadrant (1,1)
    STAGE_A(nxt, k1, 2); STAGE_A(nxt, k1, 3);
    BAR();
    MMA(1, 1);
    VMCNT(4); BAR();          // guards A0,A1,B0,B1 of next K-tile
  }
  // last K-tile (kt = 63, buf = 1): no staging, drain 4->2->0
  {
    READ_A(1, 0); READ_B(1, 0);
    BAR();
    MMA(0, 0);
    VMCNT(2); BAR();
    READ_B(1, 1);
    BAR();
    MMA(0, 1);
    VMCNT(0); BAR();
    READ_A(1, 1);
    BAR();
    MMA(1, 0);
    MMA(1, 1);
  }

  // epilogue: C col = lane&15, row = (lane>>4)*4 + r  (verified round 0)
  const int colb = n0 + wn * 64 + (lane & 15);
  const int rowb = m0 + wm * 128 + ((lane >> 4) << 2);
#pragma unroll
  for (int j = 0; j < 4; ++j) {
    const int col = colb + j * 16;
    const float bv = bias[col];
#pragma unroll
    for (int ai = 0; ai < 8; ++ai) {
      const int row = rowb + ai * 16;
#pragma unroll
      for (int r = 0; r < 4; ++r)
        out[(size_t)(row + r) * N_DIM + col] = acc[ai][j][r] + bv;
    }
  }
#undef STAGE_A
#undef STAGE_B
#undef READ_A
#undef READ_B
#undef MMA
}

// ================= fallback: round-0 128x128 inline-dequant GEMM =================
#define FBM 128
#define FBN 128
#define FBK 64
#define FNT_N 86
#define FNT_M 64
#define FNB (FNT_N * FNT_M)

__global__ __launch_bounds__(256, 2) void gemm_fb_kernel(
    const float* __restrict__ Ain, const int* __restrict__ Wcodes,
    const float* __restrict__ scales, const float* __restrict__ bias,
    float* __restrict__ out) {
  __shared__ unsigned short lsA[FBM * FBK];
  __shared__ unsigned short lsB[FBN * FBK];

  const int t = threadIdx.x;
  const int bid = blockIdx.x;
  const int wg = (bid & 7) * (FNB / 8) + (bid >> 3);
  const int m0 = (wg / FNT_N) * FBM;
  const int n0 = (wg % FNT_N) * FBN;

  const int w = t >> 6;
  const int lane = t & 63;
  const int wm = w >> 1, wn = w & 1;
  const int srow = t >> 3;
  const int sp = t & 7;
  const int skc = sp ^ (srow & 7);

  f32x4 acc[4][4];
#pragma unroll
  for (int i = 0; i < 4; ++i)
#pragma unroll
    for (int j = 0; j < 4; ++j) {
      f32x4 z = {0.f, 0.f, 0.f, 0.f};
      acc[i][j] = z;
    }

  for (int kt = 0; kt < K_DIM / FBK; ++kt) {
    const int kg = kt * FBK + skc * 8;
#pragma unroll
    for (int c = 0; c < 4; ++c) {
      const int arow = m0 + c * 32 + srow;
      const float* ap = Ain + (size_t)arow * K_DIM + kg;
      float4 a0 = *(const float4*)ap;
      float4 a1 = *(const float4*)(ap + 4);
      uint4 va;
      va.x = pk2(a0.x, a0.y); va.y = pk2(a0.z, a0.w);
      va.z = pk2(a1.x, a1.y); va.w = pk2(a1.z, a1.w);
      *(uint4*)&lsA[(c * 32 + srow) * FBK + sp * 8] = va;

      const int nrow = n0 + c * 32 + srow;
      const float s = scales[nrow * NGROUPS + (kg >> 7)];
      const int4* wp = (const int4*)(Wcodes + (size_t)nrow * K_DIM + kg);
      int4 c0 = wp[0], c1 = wp[1];
      uint4 vb;
      vb.x = pk2((float)c0.x * s, (float)c0.y * s);
      vb.y = pk2((float)c0.z * s, (float)c0.w * s);
      vb.z = pk2((float)c1.x * s, (float)c1.y * s);
      vb.w = pk2((float)c1.z * s, (float)c1.w * s);
      *(uint4*)&lsB[(c * 32 + srow) * FBK + sp * 8] = vb;
    }
    __syncthreads();
#pragma unroll
    for (int kk = 0; kk < 2; ++kk) {
      bf16x8 af[4], bfr[4];
#pragma unroll
      for (int i = 0; i < 4; ++i) {
        const int row = wm * 64 + i * 16 + (lane & 15);
        const int pg = (kk * 4 + (lane >> 4)) ^ (row & 7);
        af[i] = *(const bf16x8*)&lsA[row * FBK + pg * 8];
      }
#pragma unroll
      for (int j = 0; j < 4; ++j) {
        const int row = wn * 64 + j * 16 + (lane & 15);
        const int pg = (kk * 4 + (lane >> 4)) ^ (row & 7);
        bfr[j] = *(const bf16x8*)&lsB[row * FBK + pg * 8];
      }
#pragma unroll
      for (int i = 0; i < 4; ++i)
#pragma unroll
        for (int j = 0; j < 4; ++j)
          acc[i][j] = __builtin_amdgcn_mfma_f32_16x16x32_bf16(af[i], bfr[j], acc[i][j], 0, 0, 0);
    }
    __syncthreads();
  }

  const int colb = n0 + wn * 64 + (lane & 15);
  const int rowb = m0 + wm * 64 + ((lane >> 4) << 2);
#pragma unroll
  for (int j = 0; j < 4; ++j) {
    const int col = colb + j * 16;
    const float bv = bias[col];
#pragma unroll
    for (int i = 0; i < 4; ++i) {
      const int row = rowb + i * 16;
#pragma unroll
      for (int r = 0; r < 4; ++r)
        out[(size_t)(row + r) * N_DIM + col] = acc[i][j][r] + bv;
    }
  }
}

extern "C" void kernel_launch(void* const* d_in, const int* in_sizes, int n_in,
                              void* d_out, int out_size, void* d_ws, size_t ws_size,
                              hipStream_t stream) {
  const float* Ain = (const float*)d_in[0];
  const int* Wc = (const int*)d_in[1];
  const float* sc = (const float*)d_in[2];
  const float* bias = (const float*)d_in[3];
  float* out = (float*)d_out;

  const size_t needA = (size_t)M_DIM * K_DIM * 2;
  const size_t needB = (size_t)N_DIM * K_DIM * 2;
  if (ws_size >= needA + needB) {
    unsigned short* wsA = (unsigned short*)d_ws;
    unsigned short* wsB = (unsigned short*)((char*)d_ws + needA);
    cvtA_kernel<<<(unsigned)((size_t)M_DIM * K_DIM / 8 / 256), 256, 0, stream>>>(Ain, wsA);
    dequantW_kernel<<<(unsigned)((size_t)N_DIM * K_DIM / 8 / 256), 256, 0, stream>>>(Wc, sc, wsB);
    gemm8_kernel<<<NB2, 512, 0, stream>>>(wsA, wsB, bias, out);
  } else {
    gemm_fb_kernel<<<FNB, 256, 0, stream>>>(Ain, Wc, sc, bias, out);
  }
}